// Round 9
// baseline (84.562 us; speedup 1.0000x reference)
//
#include <hip/hip_runtime.h>

// ThinPlateSpline: out = K_query @ rbf_weights + P_query @ poly_coeffs
//   K_ij = r*ln(r), r = ||u_i - c_j|| (d=3)
//   kk = r * log2(r2),  C = 0.5*ln2 folded into staged weights.
//   r2 = usq + |c|^2 - 2 u.c (expanded form), fmax guard.
//
// R9: cross-round fit says v_sqrt/v_log each occupy ~27 issue-cyc per wave64
// (~70% of kernel time); full-rate float code issues at ~100% eff. So:
// soft-sqrt (Quake rsqrt hack + 1 Newton, 7 instr ~ 15 cyc) replaces the
// sqrt trans; keep hw v_log (software log compiles fatter than 27 cyc).
// QPT=4 with phase-split inner loop: 4 indep r2 -> 4 back-to-back v_log ->
// muls/accs; if trans actually pipelines, the 4 indep logs overlap (bonus
// + discriminator). Structure per R7 (proven): BLK=256 = 4 waves = 4
// n-splits, JCHUNK=256, grid (64,16)=1024 blocks, in-block LDS reduction,
// coalesced atomics across grid.y (786K, proven ~free).

#define BLK 256
#define NS 4            // waves per block = in-block n-splits
#define QPT 4           // queries per lane
#define QPB 256         // queries per block = 64 * QPT
#define JCHUNK 256      // j per block
#define JW (JCHUNK / NS)

__global__ __launch_bounds__(BLK, 4) void tps_kernel(
    const float* __restrict__ u,     // (batch, 3)
    const float* __restrict__ cp,    // (n, 3)
    const float* __restrict__ w,     // (n, 3)
    const float* __restrict__ poly,  // (4, 3)
    float* __restrict__ out,         // (batch, 3)
    int batch, int n)
{
    __shared__ float4 s_a[JCHUNK];         // {-2cx, -2cy, -2cz, |c|^2}
    __shared__ float4 s_b[JCHUNK];         // {C*w, 0}
    __shared__ float  s_red[NS][QPB * 3];  // per-wave partial sums (12 KB)

    const float C = 0.34657359027997264f;  // 0.5 * ln(2)

    const int tid = threadIdx.x;
    const int j0 = blockIdx.y * JCHUNK;

    {   // stage + transform this block's 256-j slice (BLK == JCHUNK)
        const int g = j0 + tid;
        const float cx = cp[g * 3 + 0], cy = cp[g * 3 + 1], cz = cp[g * 3 + 2];
        s_a[tid] = make_float4(-2.f * cx, -2.f * cy, -2.f * cz,
                               fmaf(cx, cx, fmaf(cy, cy, cz * cz)));
        s_b[tid] = make_float4(C * w[g * 3 + 0], C * w[g * 3 + 1],
                               C * w[g * 3 + 2], 0.f);
    }
    __syncthreads();

    const int lane = tid & 63;
    const int wv   = tid >> 6;    // 0..3 = n-split

    float ux[QPT], uy[QPT], uz[QPT], usq[QPT];
    float ax[QPT], ay[QPT], az[QPT];
#pragma unroll
    for (int k = 0; k < QPT; ++k) {
        const int q = blockIdx.x * QPB + k * 64 + lane;  // exact multiple
        ux[k] = u[q * 3 + 0];
        uy[k] = u[q * 3 + 1];
        uz[k] = u[q * 3 + 2];
        usq[k] = fmaf(ux[k], ux[k], fmaf(uy[k], uy[k], uz[k] * uz[k]));
        ax[k] = ay[k] = az[k] = 0.f;
    }

    if (blockIdx.y == 0 && wv == 0) {  // polynomial term exactly once
#pragma unroll
        for (int k = 0; k < QPT; ++k) {
            ax[k] = poly[0] + ux[k] * poly[3] + uy[k] * poly[6] + uz[k] * poly[9];
            ay[k] = poly[1] + ux[k] * poly[4] + uy[k] * poly[7] + uz[k] * poly[10];
            az[k] = poly[2] + ux[k] * poly[5] + uy[k] * poly[8] + uz[k] * poly[11];
        }
    }

    const int jlo = wv * JW;
#pragma unroll 4
    for (int j = jlo; j < jlo + JW; ++j) {
        const float4 A = s_a[j];   // wave-uniform broadcast, ds_read_b128
        const float4 B = s_b[j];

        float r2[QPT], rr[QPT], lg[QPT];
        // Phase 1: 4 independent r2
#pragma unroll
        for (int k = 0; k < QPT; ++k) {
            float t = fmaf(A.x, ux[k],
                      fmaf(A.y, uy[k],
                      fmaf(A.z, uz[k], A.w + usq[k])));
            r2[k] = fmaxf(t, 1e-30f);
        }
        // Phase 2: soft sqrt (rsqrt bit-hack + 1 Newton), r = t * y
#pragma unroll
        for (int k = 0; k < QPT; ++k) {
            const float t = r2[k];
            float y = __int_as_float(0x5f3759df - (__float_as_int(t) >> 1));
            y = y * fmaf(-0.5f * t, y * y, 1.5f);
            rr[k] = t * y;
        }
        // Phase 3: 4 back-to-back independent hw logs
#pragma unroll
        for (int k = 0; k < QPT; ++k)
            lg[k] = __builtin_amdgcn_logf(r2[k]);
        // Phase 4: accumulate
#pragma unroll
        for (int k = 0; k < QPT; ++k) {
            const float kk = rr[k] * lg[k];
            ax[k] = fmaf(kk, B.x, ax[k]);
            ay[k] = fmaf(kk, B.y, ay[k]);
            az[k] = fmaf(kk, B.z, az[k]);
        }
    }

    // In-block reduction across the 4 n-split waves.
#pragma unroll
    for (int k = 0; k < QPT; ++k) {
        const int base = (k * 64 + lane) * 3;
        s_red[wv][base + 0] = ax[k];
        s_red[wv][base + 1] = ay[k];
        s_red[wv][base + 2] = az[k];
    }
    __syncthreads();

    for (int v = tid; v < QPB * 3; v += BLK) {
        float s = s_red[0][v] + s_red[1][v] + s_red[2][v] + s_red[3][v];
        atomicAdd(&out[(size_t)blockIdx.x * (QPB * 3) + v], s);
    }
}

extern "C" void kernel_launch(void* const* d_in, const int* in_sizes, int n_in,
                              void* d_out, int out_size, void* d_ws, size_t ws_size,
                              hipStream_t stream) {
    const float* u    = (const float*)d_in[0];  // (batch,3)
    const float* cp   = (const float*)d_in[1];  // (n,3)
    const float* w    = (const float*)d_in[2];  // (n,3)
    const float* poly = (const float*)d_in[3];  // (4,3)
    float* out = (float*)d_out;

    const int batch = in_sizes[0] / 3;  // 16384
    const int n     = in_sizes[1] / 3;  // 4096

    hipMemsetAsync(d_out, 0, (size_t)out_size * sizeof(float), stream);

    dim3 block(BLK);
    dim3 grid(batch / QPB, n / JCHUNK);  // (64, 16) = 1024 blocks
    tps_kernel<<<grid, block, 0, stream>>>(u, cp, w, poly, out, batch, n);
}